// Round 14
// baseline (2411.174 us; speedup 1.0000x reference)
//
#include <hip/hip_runtime.h>
#include <cstdint>
#include <cstddef>

#define SEQT  512
#define HID   1024
#define G3    3072
#define HSTR  1080   // h_lds row stride in shorts (2160 B, 16B-aligned)
#define RING  32     // xgs ring depth
#define FSTR  32     // flag stride in u32 (128 B)

typedef __attribute__((ext_vector_type(8))) short bf16x8;
typedef __attribute__((ext_vector_type(8))) unsigned short u16x8;
typedef __attribute__((ext_vector_type(4))) float f32x4;

__device__ __forceinline__ float sigm(float x){ return 1.0f/(1.0f+expf(-x)); }
__device__ __forceinline__ float b2f(unsigned short s){ return __uint_as_float(((uint32_t)s)<<16); }
__device__ __forceinline__ unsigned short f2b(float f){
    uint32_t u=__float_as_uint(f);
    return (unsigned short)((u + 0x7FFFu + ((u>>16)&1u))>>16);
}

// ---------------------------------------------------------------------------
// MFMA GEMM (proven since R3). ASRC: 1=f32 reg-staged, 2=bf16 + (1+gate) fuse.
// BSRC: 1=f32 reg-staged. MODE: 0=f32+bias, 1=bf16 tanh(+bias+ctx).
// ---------------------------------------------------------------------------
template<int ASRC, int BSRC, int MODE>
__global__ __launch_bounds__(256) void mfma_gemm(
    const void* __restrict__ Av, const void* __restrict__ Bv,
    const float* __restrict__ bias, const float* __restrict__ ctx,
    const float* __restrict__ gate, void* __restrict__ Cv,
    int N, int K)
{
    __shared__ __align__(16) unsigned short As[128*64];
    __shared__ __align__(16) unsigned short Bs[128*64];
    const int tid = threadIdx.x;
    const int lane = tid & 63;
    const int w = tid >> 6;
    const int wm = w & 1, wn = w >> 1;
    const int m0 = blockIdx.y * 128, n0 = blockIdx.x * 128;

    f32x4 acc[4][4];
#pragma unroll
    for (int i = 0; i < 4; i++)
#pragma unroll
        for (int j = 0; j < 4; j++) acc[i][j] = (f32x4){0.f,0.f,0.f,0.f};

    for (int kt = 0; kt < K; kt += 64) {
        __syncthreads();
        if (ASRC == 1) {
            const float* Af = (const float*)Av;
#pragma unroll
            for (int p = 0; p < 4; p++) {
                const int q = p*256 + tid, row = q>>3, kc = q&7;
                const float* src = Af + (size_t)(m0+row)*K + kt + kc*8;
                float4 u = *(const float4*)src, v = *(const float4*)(src+4);
                __align__(16) unsigned short tmp[8] =
                    {f2b(u.x),f2b(u.y),f2b(u.z),f2b(u.w),f2b(v.x),f2b(v.y),f2b(v.z),f2b(v.w)};
                *(bf16x8*)&As[row*64 + kc*8] = *(const bf16x8*)tmp;
            }
        } else {
            const unsigned short* Ab = (const unsigned short*)Av;
#pragma unroll
            for (int p = 0; p < 4; p++) {
                const int q = p*256 + tid, row = q>>3, kc = q&7;
                const int b = (m0+row) >> 9;
                u16x8 hv = *(const u16x8*)(Ab + (size_t)(m0+row)*K + kt + kc*8);
                const float* gp = gate + (size_t)b*HID + kt + kc*8;
                float4 g0 = *(const float4*)gp, g1 = *(const float4*)(gp+4);
                const float gg[8] = {g0.x,g0.y,g0.z,g0.w,g1.x,g1.y,g1.z,g1.w};
                __align__(16) unsigned short tmp[8];
#pragma unroll
                for (int e = 0; e < 8; e++)
                    tmp[e] = f2b(b2f(hv[e]) * (1.0f + gg[e]));
                *(bf16x8*)&As[row*64 + kc*8] = *(const bf16x8*)tmp;
            }
        }
        {
            const float* Bf = (const float*)Bv;
#pragma unroll
            for (int p = 0; p < 4; p++) {
                const int q = p*256 + tid, row = q>>3, kc = q&7;
                const float* src = Bf + (size_t)(n0+row)*K + kt + kc*8;
                float4 u = *(const float4*)src, v = *(const float4*)(src+4);
                __align__(16) unsigned short tmp[8] =
                    {f2b(u.x),f2b(u.y),f2b(u.z),f2b(u.w),f2b(v.x),f2b(v.y),f2b(v.z),f2b(v.w)};
                *(bf16x8*)&Bs[row*64 + kc*8] = *(const bf16x8*)tmp;
            }
        }
        __syncthreads();
#pragma unroll
        for (int kg = 0; kg < 2; kg++) {
            bf16x8 af[4], bfr[4];
#pragma unroll
            for (int mi = 0; mi < 4; mi++)
                af[mi] = *(const bf16x8*)&As[(wm*64+mi*16+(lane&15))*64 + kg*32 + (lane>>4)*8];
#pragma unroll
            for (int ni = 0; ni < 4; ni++)
                bfr[ni] = *(const bf16x8*)&Bs[(wn*64+ni*16+(lane&15))*64 + kg*32 + (lane>>4)*8];
#pragma unroll
            for (int mi = 0; mi < 4; mi++)
#pragma unroll
                for (int ni = 0; ni < 4; ni++)
                    acc[mi][ni] = __builtin_amdgcn_mfma_f32_16x16x32_bf16(
                        af[mi], bfr[ni], acc[mi][ni], 0, 0, 0);
        }
    }

    const int cl = lane & 15, rg = lane >> 4;
    const int bct = m0 >> 9;
#pragma unroll
    for (int mi = 0; mi < 4; mi++) {
        const int rowb = m0 + wm*64 + mi*16 + rg*4;
#pragma unroll
        for (int ni = 0; ni < 4; ni++) {
            const int col = n0 + wn*64 + ni*16 + cl;
            const float bv = bias[col];
            const float cv = (MODE==1) ? ctx[(size_t)bct*HID + col] : 0.0f;
#pragma unroll
            for (int r = 0; r < 4; r++) {
                float val = acc[mi][ni][r] + bv;
                if (MODE==1) val = tanhf(val + cv);
                const size_t off = (size_t)(rowb+r)*N + col;
                if (MODE==0) ((float*)Cv)[off] = val;
                else ((unsigned short*)Cv)[off] = f2b(val);
            }
        }
    }
}

// ---------------------------------------------------------------------------
__global__ __launch_bounds__(256) void gate_kernel(
    const float* __restrict__ ctx, const float* __restrict__ Wg,
    const float* __restrict__ bg, float* __restrict__ gate)
{
    const int j = blockIdx.x * 256 + threadIdx.x;
    const int b = blockIdx.y;
    const float4* cp = (const float4*)(ctx + (size_t)b * HID);
    const float4* wp = (const float4*)(Wg + (size_t)j * HID);
    float acc = 0.0f;
#pragma unroll 4
    for (int k = 0; k < HID / 4; k++) {
        float4 c = cp[k], w = wp[k];
        acc += c.x * w.x + c.y * w.y + c.z * w.z + c.w * w.w;
    }
    gate[(size_t)b * HID + j] = sigm(acc + bg[j]);
}

__device__ __forceinline__ void poll_ge(const unsigned int* p, unsigned int tgt)
{
    while (__hip_atomic_load(p, __ATOMIC_RELAXED, __HIP_MEMORY_SCOPE_AGENT) < tgt)
        __builtin_amdgcn_s_sleep(2);
}

// ---------------------------------------------------------------------------
// 4-stage pipelined GRU. R12/R13 base + NEW: R stages process two batch
// groups (A=b0-15, B=b16-31) in ping-pong phases, hiding publish/visibility
// latency of one group under the other group's stage+compute. Publish-ack
// rides the NEXT phase's vmcnt(0); flag set one half-phase later (full phase
// of slack remains before peers consume).
// Flags: 0:fP0 1:fR0A 2:fR0B 3:fP1 4:fR1A 5:fR1B.
//   fRA[rb]=t+1 set at B(t) after A(t)-publish acked.
//   fRB[rb]=t   set at A(t) after B(t-1)-publish acked (epilogue sets SEQT).
// ---------------------------------------------------------------------------
__global__ __launch_bounds__(384, 1) void gru_pipe(
    const float* __restrict__ Wih0, const float* __restrict__ Whh0,
    const float* __restrict__ bih0, const float* __restrict__ bhh0,
    const float* __restrict__ Wih1, const float* __restrict__ Whh1,
    const float* __restrict__ bih1, const float* __restrict__ bhh1,
    const unsigned short* __restrict__ mixed,   // [B*T][H] bf16
    unsigned short* __restrict__ h1,
    unsigned short* __restrict__ h2,
    unsigned short* __restrict__ xgs0,          // [64][RING][32][48] bf16
    unsigned short* __restrict__ xgs1,
    unsigned int* __restrict__ flags)           // 6 sets x 64 x FSTR u32
{
    __shared__ __align__(16) unsigned short h_lds[32*HSTR];
    __shared__ float sc[1632];                  // P:[3][32][17]  R:[6][16][17]
    const int tid = threadIdx.x;
    const int lane = tid & 63;
    const int w = tid >> 6;
    const int bid = blockIdx.x;
    const int role = bid >> 6, rb = bid & 63;
    const int j0 = rb * 16;
    const int cl = lane & 15, kq = lane >> 4;

    unsigned int* fset[6] = { flags,            flags + 64*FSTR,  flags + 128*FSTR,
                              flags + 192*FSTR, flags + 256*FSTR, flags + 320*FSTR };

    if ((role & 1) == 0) {
        // ================= producer: xg = Wih @ hsrc[t] ===================
        const int g = w >> 1, mh = w & 1;
        const float* Wsrc = (role == 0) ? Wih0 : Wih1;
        bf16x8 wreg[32];
        {
            const float* wr = Wsrc + (size_t)(g*1024 + j0 + cl)*1024 + kq*8;
#pragma unroll
            for (int kg = 0; kg < 32; kg++) {
                float4 u = *(const float4*)(wr + (size_t)kg*32);
                float4 v = *(const float4*)(wr + (size_t)kg*32 + 4);
                __align__(16) unsigned short tmp[8] =
                    {f2b(u.x),f2b(u.y),f2b(u.z),f2b(u.w),f2b(v.x),f2b(v.y),f2b(v.z),f2b(v.w)};
                wreg[kg] = *(const bf16x8*)tmp;
            }
        }
#pragma unroll
        for (int kg = 0; kg < 32; kg++) asm volatile("" : "+v"(wreg[kg]));

        const int hrow_r = mh*16 + cl;
        const unsigned short* habase =
            &h_lds[hrow_r*HSTR + ((hrow_r & 3) << 4) + kq*8];

        const unsigned short* hsrc = (role == 0) ? mixed : h1;
        unsigned short* xgs = ((role == 0) ? xgs0 : xgs1) + (size_t)rb*RING*32*48;
        const unsigned int* waitin = (role == 2) ? fset[2] : nullptr; // P1 waits fR0B
        const unsigned int* bp     = (role == 0) ? fset[2] : fset[5]; // consumer R B-flag
        unsigned int* myflag = &fset[role == 0 ? 0 : 3][rb*FSTR];

        for (int t = 0; t < SEQT; t++) {
            if (w == 0 && waitin)
                poll_ge(&waitin[lane*FSTR], (unsigned)(t+1));
            if (w == 1 && t >= RING && (t & 7) == 0)
                poll_ge(&bp[lane*FSTR], (unsigned)(t - 24));
            __syncthreads();

            for (int c = w; c < 64; c += 6) {
                const int r = c >> 1, hf = c & 1;
                const unsigned short* src =
                    hsrc + ((size_t)r*SEQT + t)*HID + hf*512 + lane*8;
                __builtin_amdgcn_global_load_lds(
                    (const __attribute__((address_space(1))) void*)src,
                    (__attribute__((address_space(3))) void*)
                        &h_lds[r*HSTR + ((r & 3) << 4) + hf*512],
                    16, 0, 0);
            }
            asm volatile("s_waitcnt vmcnt(0)" ::: "memory");
            __syncthreads();

            f32x4 A[4];
#pragma unroll
            for (int i = 0; i < 4; i++) A[i] = (f32x4){0.f,0.f,0.f,0.f};
#pragma unroll
            for (int kg = 0; kg < 32; kg++) {
                bf16x8 hv = *(const bf16x8*)(habase + kg*32);
                A[kg & 3] = __builtin_amdgcn_mfma_f32_16x16x32_bf16(
                    hv, wreg[kg], A[kg & 3], 0, 0, 0);
            }
            f32x4 av = (A[0] + A[1]) + (A[2] + A[3]);
#pragma unroll
            for (int r = 0; r < 4; r++)
                sc[(g*32 + mh*16 + kq*4 + r)*17 + cl] = av[r];
            __syncthreads();

            if (tid < 192) {
                const int b = tid / 6, c16 = (tid % 6) * 8;
                unsigned short v[8];
#pragma unroll
                for (int k = 0; k < 8; k++) {
                    const int col = c16 + k;
                    v[k] = f2b(sc[((col >> 4)*32 + b)*17 + (col & 15)]);
                }
                const uint64_t lo = (uint64_t)v[0] | ((uint64_t)v[1]<<16)
                                  | ((uint64_t)v[2]<<32) | ((uint64_t)v[3]<<48);
                const uint64_t hi = (uint64_t)v[4] | ((uint64_t)v[5]<<16)
                                  | ((uint64_t)v[6]<<32) | ((uint64_t)v[7]<<48);
                uint64_t* dst = (uint64_t*)(xgs + (((size_t)(t & (RING-1))*32 + b)*48 + c16));
                __hip_atomic_store(dst,   lo, __ATOMIC_RELAXED, __HIP_MEMORY_SCOPE_AGENT);
                __hip_atomic_store(dst+1, hi, __ATOMIC_RELAXED, __HIP_MEMORY_SCOPE_AGENT);
            }
            asm volatile("s_waitcnt vmcnt(0)" ::: "memory");
            __syncthreads();
            if (tid == 0)
                __hip_atomic_store(myflag, (unsigned)(t+1),
                                   __ATOMIC_RELAXED, __HIP_MEMORY_SCOPE_AGENT);
        }
    } else {
        // ========== recurrent: two-group (A/B) ping-pong phases ===========
        const int g = w >> 1, kh = w & 1;     // 3 gates x 2 K-halves
        const float* Wsrc = (role == 1) ? Whh0 : Whh1;
        bf16x8 wreg[16];
        {
            const float* wr = Wsrc + (size_t)(g*1024 + j0 + cl)*1024 + kh*512 + kq*8;
#pragma unroll
            for (int kg = 0; kg < 16; kg++) {
                float4 u = *(const float4*)(wr + (size_t)kg*32);
                float4 v = *(const float4*)(wr + (size_t)kg*32 + 4);
                __align__(16) unsigned short tmp[8] =
                    {f2b(u.x),f2b(u.y),f2b(u.z),f2b(u.w),f2b(v.x),f2b(v.y),f2b(v.z),f2b(v.w)};
                wreg[kg] = *(const bf16x8*)tmp;
            }
        }
#pragma unroll
        for (int kg = 0; kg < 16; kg++) asm volatile("" : "+v"(wreg[kg]));

        unsigned short* hdst = (role == 1) ? h1 : h2;
        const unsigned short* xgs = ((role == 1) ? xgs0 : xgs1) + (size_t)rb*RING*32*48;
        const float* bih = (role == 1) ? bih0 : bih1;
        const float* bhh = (role == 1) ? bhh0 : bhh1;
        const unsigned int* prodf  = &fset[role == 1 ? 0 : 3][rb*FSTR];
        unsigned int* setA = fset[role == 1 ? 1 : 4];
        unsigned int* setB = fset[role == 1 ? 2 : 5];
        unsigned int* myflagA = &setA[rb*FSTR];
        unsigned int* myflagB = &setB[rb*FSTR];

        // read bases: group A rows 0-15, group B rows 16-31 (physical)
        const unsigned short* habaseA =
            &h_lds[cl*HSTR + ((cl & 3) << 4) + kh*512 + kq*8];
        const unsigned short* habaseB =
            &h_lds[(16 + cl)*HSTR + ((cl & 3) << 4) + kh*512 + kq*8];

        const int fb = tid >> 3;              // 0..15 batch-in-group
        const int fj = (tid & 7) * 2;
        float hpA0=0.f, hpA1=0.f, hpB0=0.f, hpB1=0.f;
        float br0=0,br1=0,bz0=0,bz1=0,bni0=0,bni1=0,bnh0=0,bnh1=0;
        if (tid < 128) {
            br0 = bih[j0+fj]        + bhh[j0+fj];
            br1 = bih[j0+fj+1]      + bhh[j0+fj+1];
            bz0 = bih[HID+j0+fj]    + bhh[HID+j0+fj];
            bz1 = bih[HID+j0+fj+1]  + bhh[HID+j0+fj+1];
            bni0 = bih[2*HID+j0+fj];   bni1 = bih[2*HID+j0+fj+1];
            bnh0 = bhh[2*HID+j0+fj];   bnh1 = bhh[2*HID+j0+fj+1];
        }

        for (int t = 0; t < SEQT; t++) {
            // ======================= A-phase ==============================
            if (w == 0 && t > 0)
                poll_ge(&setA[lane*FSTR], (unsigned)t);         // peers A[t-1]
            if (w == 2 && lane == 0)
                poll_ge(prodf, (unsigned)(t+1));                // xg[t] ready
            __syncthreads();

            uint32_t xr2=0, xz2=0, xn2=0;
            if (tid < 128) {
                const unsigned short* xp =
                    xgs + ((size_t)(t & (RING-1))*32 + fb)*48;  // batch fb (A)
                xr2 = __hip_atomic_load((const unsigned int*)(xp + fj),
                                        __ATOMIC_RELAXED, __HIP_MEMORY_SCOPE_AGENT);
                xz2 = __hip_atomic_load((const unsigned int*)(xp + 16 + fj),
                                        __ATOMIC_RELAXED, __HIP_MEMORY_SCOPE_AGENT);
                xn2 = __hip_atomic_load((const unsigned int*)(xp + 32 + fj),
                                        __ATOMIC_RELAXED, __HIP_MEMORY_SCOPE_AGENT);
            }
            if (t > 0) {
                for (int c = w; c < 32; c += 6) {               // stage A[t-1]
                    const int r = c >> 1, hf = c & 1;           // rows 0-15
                    const unsigned short* src =
                        hdst + ((size_t)r*SEQT + (t-1))*HID + hf*512 + lane*8;
                    __builtin_amdgcn_global_load_lds(
                        (const __attribute__((address_space(1))) void*)src,
                        (__attribute__((address_space(3))) void*)
                            &h_lds[r*HSTR + ((r & 3) << 4) + hf*512],
                        16, 0, 0);
                }
            }
            asm volatile("s_waitcnt vmcnt(0)" ::: "memory");    // + acks B(t-1) publish
            __syncthreads();
            if (tid == 0)
                __hip_atomic_store(myflagB, (unsigned)t,        // B[t-1] visible
                                   __ATOMIC_RELAXED, __HIP_MEMORY_SCOPE_AGENT);

            f32x4 A[4];
#pragma unroll
            for (int i = 0; i < 4; i++) A[i] = (f32x4){0.f,0.f,0.f,0.f};
            if (t > 0) {
#pragma unroll
                for (int kg = 0; kg < 16; kg++) {
                    bf16x8 hv = *(const bf16x8*)(habaseA + kg*32);
                    A[kg & 3] = __builtin_amdgcn_mfma_f32_16x16x32_bf16(
                        hv, wreg[kg], A[kg & 3], 0, 0, 0);
                }
            }
            f32x4 av = (A[0] + A[1]) + (A[2] + A[3]);
#pragma unroll
            for (int r = 0; r < 4; r++)
                sc[((g*2 + kh)*16 + kq*4 + r)*17 + cl] = av[r];
            __syncthreads();

            if (tid < 128) {
                const float sr0 = sc[(0*16+fb)*17+fj]   + sc[(1*16+fb)*17+fj];
                const float sr1 = sc[(0*16+fb)*17+fj+1] + sc[(1*16+fb)*17+fj+1];
                const float sz0 = sc[(2*16+fb)*17+fj]   + sc[(3*16+fb)*17+fj];
                const float sz1 = sc[(2*16+fb)*17+fj+1] + sc[(3*16+fb)*17+fj+1];
                const float sn0 = sc[(4*16+fb)*17+fj]   + sc[(5*16+fb)*17+fj];
                const float sn1 = sc[(4*16+fb)*17+fj+1] + sc[(5*16+fb)*17+fj+1];
                const float r0 = sigm(b2f((unsigned short)(xr2 & 0xFFFF)) + sr0 + br0);
                const float r1 = sigm(b2f((unsigned short)(xr2 >> 16))    + sr1 + br1);
                const float z0 = sigm(b2f((unsigned short)(xz2 & 0xFFFF)) + sz0 + bz0);
                const float z1 = sigm(b2f((unsigned short)(xz2 >> 16))    + sz1 + bz1);
                const float n0 = tanhf(b2f((unsigned short)(xn2 & 0xFFFF)) + bni0 + r0*(sn0 + bnh0));
                const float n1 = tanhf(b2f((unsigned short)(xn2 >> 16))    + bni1 + r1*(sn1 + bnh1));
                const float h0 = (1.0f - z0)*n0 + z0*hpA0;
                const float h1v = (1.0f - z1)*n1 + z1*hpA1;
                hpA0 = h0; hpA1 = h1v;
                const uint32_t hv = (uint32_t)f2b(h0) | ((uint32_t)f2b(h1v) << 16);
                uint32_t* dst = (uint32_t*)(hdst + ((size_t)fb*SEQT + t)*HID + j0 + fj);
                __hip_atomic_store(dst, hv, __ATOMIC_RELAXED, __HIP_MEMORY_SCOPE_AGENT);
            }

            // ======================= B-phase ==============================
            if (w == 0 && t > 0)
                poll_ge(&setB[lane*FSTR], (unsigned)t);         // peers B[t-1]
            __syncthreads();

            if (tid < 128) {
                const unsigned short* xp =
                    xgs + ((size_t)(t & (RING-1))*32 + 16 + fb)*48;  // batch 16+fb
                xr2 = __hip_atomic_load((const unsigned int*)(xp + fj),
                                        __ATOMIC_RELAXED, __HIP_MEMORY_SCOPE_AGENT);
                xz2 = __hip_atomic_load((const unsigned int*)(xp + 16 + fj),
                                        __ATOMIC_RELAXED, __HIP_MEMORY_SCOPE_AGENT);
                xn2 = __hip_atomic_load((const unsigned int*)(xp + 32 + fj),
                                        __ATOMIC_RELAXED, __HIP_MEMORY_SCOPE_AGENT);
            }
            if (t > 0) {
                for (int c = w; c < 32; c += 6) {               // stage B[t-1]
                    const int r = c >> 1, hf = c & 1;
                    const int pr = 16 + r;                      // rows 16-31
                    const unsigned short* src =
                        hdst + ((size_t)(16 + r)*SEQT + (t-1))*HID + hf*512 + lane*8;
                    __builtin_amdgcn_global_load_lds(
                        (const __attribute__((address_space(1))) void*)src,
                        (__attribute__((address_space(3))) void*)
                            &h_lds[pr*HSTR + ((pr & 3) << 4) + hf*512],
                        16, 0, 0);
                }
            }
            asm volatile("s_waitcnt vmcnt(0)" ::: "memory");    // + acks A(t) publish
            __syncthreads();
            if (tid == 0)
                __hip_atomic_store(myflagA, (unsigned)(t+1),    // A[t] visible
                                   __ATOMIC_RELAXED, __HIP_MEMORY_SCOPE_AGENT);

#pragma unroll
            for (int i = 0; i < 4; i++) A[i] = (f32x4){0.f,0.f,0.f,0.f};
            if (t > 0) {
#pragma unroll
                for (int kg = 0; kg < 16; kg++) {
                    bf16x8 hv = *(const bf16x8*)(habaseB + kg*32);
                    A[kg & 3] = __builtin_amdgcn_mfma_f32_16x16x32_bf16(
                        hv, wreg[kg], A[kg & 3], 0, 0, 0);
                }
            }
            av = (A[0] + A[1]) + (A[2] + A[3]);
#pragma unroll
            for (int r = 0; r < 4; r++)
                sc[((g*2 + kh)*16 + kq*4 + r)*17 + cl] = av[r];
            __syncthreads();

            if (tid < 128) {
                const float sr0 = sc[(0*16+fb)*17+fj]   + sc[(1*16+fb)*17+fj];
                const float sr1 = sc[(0*16+fb)*17+fj+1] + sc[(1*16+fb)*17+fj+1];
                const float sz0 = sc[(2*16+fb)*17+fj]   + sc[(3*16+fb)*17+fj];
                const float sz1 = sc[(2*16+fb)*17+fj+1] + sc[(3*16+fb)*17+fj+1];
                const float sn0 = sc[(4*16+fb)*17+fj]   + sc[(5*16+fb)*17+fj];
                const float sn1 = sc[(4*16+fb)*17+fj+1] + sc[(5*16+fb)*17+fj+1];
                const float r0 = sigm(b2f((unsigned short)(xr2 & 0xFFFF)) + sr0 + br0);
                const float r1 = sigm(b2f((unsigned short)(xr2 >> 16))    + sr1 + br1);
                const float z0 = sigm(b2f((unsigned short)(xz2 & 0xFFFF)) + sz0 + bz0);
                const float z1 = sigm(b2f((unsigned short)(xz2 >> 16))    + sz1 + bz1);
                const float n0 = tanhf(b2f((unsigned short)(xn2 & 0xFFFF)) + bni0 + r0*(sn0 + bnh0));
                const float n1 = tanhf(b2f((unsigned short)(xn2 >> 16))    + bni1 + r1*(sn1 + bnh1));
                const float h0 = (1.0f - z0)*n0 + z0*hpB0;
                const float h1v = (1.0f - z1)*n1 + z1*hpB1;
                hpB0 = h0; hpB1 = h1v;
                const uint32_t hv = (uint32_t)f2b(h0) | ((uint32_t)f2b(h1v) << 16);
                uint32_t* dst = (uint32_t*)(hdst + ((size_t)(16+fb)*SEQT + t)*HID + j0 + fj);
                __hip_atomic_store(dst, hv, __ATOMIC_RELAXED, __HIP_MEMORY_SCOPE_AGENT);
            }
        }
        // epilogue: flush + flag final B so P1 can consume h1[SEQT-1]
        asm volatile("s_waitcnt vmcnt(0)" ::: "memory");
        __syncthreads();
        if (tid == 0)
            __hip_atomic_store(myflagB, (unsigned)SEQT,
                               __ATOMIC_RELAXED, __HIP_MEMORY_SCOPE_AGENT);
    }
}

// ---------------------------------------------------------------------------
__global__ __launch_bounds__(256) void diag_kernel(float* __restrict__ out,
                                                   int n, float code)
{
    for (int i = blockIdx.x * 256 + threadIdx.x; i < n; i += gridDim.x * 256)
        out[i] = (i == 0) ? code : 0.0f;
}

// ---------------------------------------------------------------------------
extern "C" void kernel_launch(void* const* d_in, const int* in_sizes, int n_in,
                              void* d_out, int out_size, void* d_ws, size_t ws_size,
                              hipStream_t stream)
{
    const float* x      = (const float*)d_in[0];
    const float* ctx    = (const float*)d_in[1];
    const float* W_in   = (const float*)d_in[2];
    const float* b_in   = (const float*)d_in[3];
    const float* Wih0   = (const float*)d_in[4];
    const float* Whh0   = (const float*)d_in[5];
    const float* bih0   = (const float*)d_in[6];
    const float* bhh0   = (const float*)d_in[7];
    const float* Wih1   = (const float*)d_in[8];
    const float* Whh1   = (const float*)d_in[9];
    const float* bih1   = (const float*)d_in[10];
    const float* bhh1   = (const float*)d_in[11];
    const float* W_out  = (const float*)d_in[12];
    const float* b_out  = (const float*)d_in[13];
    const float* W_gate = (const float*)d_in[14];
    const float* b_gate = (const float*)d_in[15];
    float* out = (float*)d_out;

    const size_t MX = (size_t)16384 * 1024 * 2;                 // 32 MiB
    const size_t XS = (size_t)64 * RING * 32 * 48 * 2;          // 6 MiB
    const size_t GT = (size_t)32 * 1024 * 4;
    const size_t FL = (size_t)6 * 64 * FSTR * 4;                // 48 KiB
    const size_t need = 3*MX + 2*XS + GT + FL;

    if (ws_size < need) {
        diag_kernel<<<2048, 256, 0, stream>>>(out, out_size, (float)(ws_size >> 20));
        return;
    }

    char* ws = (char*)d_ws;
    unsigned short* mixed = (unsigned short*)ws;
    unsigned short* h1    = (unsigned short*)(ws + MX);
    unsigned short* h2    = (unsigned short*)(ws + 2*MX);
    unsigned short* xgs0  = (unsigned short*)(ws + 3*MX);
    unsigned short* xgs1  = (unsigned short*)(ws + 3*MX + XS);
    float*          gate  = (float*)(ws + 3*MX + 2*XS);
    unsigned int*   flags = (unsigned int*)(ws + 3*MX + 2*XS + GT);

    hipMemsetAsync(flags, 0, FL, stream);
    gate_kernel<<<dim3(4, 32), 256, 0, stream>>>(ctx, W_gate, b_gate, gate);

    // mixed = tanh(x @ W_in^T + b_in + ctx[b]) -> bf16
    mfma_gemm<1, 1, 1><<<dim3(8, 128), 256, 0, stream>>>(
        x, W_in, b_in, ctx, nullptr, mixed, 1024, 1024);

    // 4-stage pipelined GRU section (two-group ping-pong R stages)
    gru_pipe<<<256, 384, 0, stream>>>(
        Wih0, Whh0, bih0, bhh0, Wih1, Whh1, bih1, bhh1,
        mixed, h1, h2, xgs0, xgs1, flags);

    // out = (h2 * (1+gate)) @ W_out^T + b_out -> f32
    mfma_gemm<2, 1, 0><<<dim3(8, 128), 256, 0, stream>>>(
        h2, W_out, b_out, nullptr, gate, out, 1024, 1024);
}

// Round 15
// 2103.103 us; speedup vs baseline: 1.1465x; 1.1465x over previous
//
#include <hip/hip_runtime.h>
#include <cstdint>
#include <cstddef>

#define SEQT  512
#define HID   1024
#define HSTR  1088   // h_lds row stride in shorts (2176 B = 17*128 -> rows bank-align, XOR swizzle spreads)
#define RING  32     // xg ring depth
#define FSTR  32     // flag stride in u32 (128 B)
#define RS    ((size_t)RING * 16 * 3072)   // ring shorts per half-layer

typedef __attribute__((ext_vector_type(8))) short bf16x8;
typedef __attribute__((ext_vector_type(8))) unsigned short u16x8;
typedef __attribute__((ext_vector_type(4))) float f32x4;

__device__ __forceinline__ float sigm(float x){ return 1.0f/(1.0f+expf(-x)); }
__device__ __forceinline__ float b2f(unsigned short s){ return __uint_as_float(((uint32_t)s)<<16); }
__device__ __forceinline__ unsigned short f2b(float f){
    uint32_t u=__float_as_uint(f);
    return (unsigned short)((u + 0x7FFFu + ((u>>16)&1u))>>16);
}

// ---------------------------------------------------------------------------
// MFMA GEMM (proven since R3). ASRC: 1=f32 reg-staged, 2=bf16 + (1+gate) fuse.
// BSRC: 1=f32 reg-staged. MODE: 0=f32+bias, 1=bf16 tanh(+bias+ctx).
// ---------------------------------------------------------------------------
template<int ASRC, int BSRC, int MODE>
__global__ __launch_bounds__(256) void mfma_gemm(
    const void* __restrict__ Av, const void* __restrict__ Bv,
    const float* __restrict__ bias, const float* __restrict__ ctx,
    const float* __restrict__ gate, void* __restrict__ Cv,
    int N, int K)
{
    __shared__ __align__(16) unsigned short As[128*64];
    __shared__ __align__(16) unsigned short Bs[128*64];
    const int tid = threadIdx.x;
    const int lane = tid & 63;
    const int w = tid >> 6;
    const int wm = w & 1, wn = w >> 1;
    const int m0 = blockIdx.y * 128, n0 = blockIdx.x * 128;

    f32x4 acc[4][4];
#pragma unroll
    for (int i = 0; i < 4; i++)
#pragma unroll
        for (int j = 0; j < 4; j++) acc[i][j] = (f32x4){0.f,0.f,0.f,0.f};

    for (int kt = 0; kt < K; kt += 64) {
        __syncthreads();
        if (ASRC == 1) {
            const float* Af = (const float*)Av;
#pragma unroll
            for (int p = 0; p < 4; p++) {
                const int q = p*256 + tid, row = q>>3, kc = q&7;
                const float* src = Af + (size_t)(m0+row)*K + kt + kc*8;
                float4 u = *(const float4*)src, v = *(const float4*)(src+4);
                __align__(16) unsigned short tmp[8] =
                    {f2b(u.x),f2b(u.y),f2b(u.z),f2b(u.w),f2b(v.x),f2b(v.y),f2b(v.z),f2b(v.w)};
                *(bf16x8*)&As[row*64 + kc*8] = *(const bf16x8*)tmp;
            }
        } else {
            const unsigned short* Ab = (const unsigned short*)Av;
#pragma unroll
            for (int p = 0; p < 4; p++) {
                const int q = p*256 + tid, row = q>>3, kc = q&7;
                const int b = (m0+row) >> 9;
                u16x8 hv = *(const u16x8*)(Ab + (size_t)(m0+row)*K + kt + kc*8);
                const float* gp = gate + (size_t)b*HID + kt + kc*8;
                float4 g0 = *(const float4*)gp, g1 = *(const float4*)(gp+4);
                const float gg[8] = {g0.x,g0.y,g0.z,g0.w,g1.x,g1.y,g1.z,g1.w};
                __align__(16) unsigned short tmp[8];
#pragma unroll
                for (int e = 0; e < 8; e++)
                    tmp[e] = f2b(b2f(hv[e]) * (1.0f + gg[e]));
                *(bf16x8*)&As[row*64 + kc*8] = *(const bf16x8*)tmp;
            }
        }
        {
            const float* Bf = (const float*)Bv;
#pragma unroll
            for (int p = 0; p < 4; p++) {
                const int q = p*256 + tid, row = q>>3, kc = q&7;
                const float* src = Bf + (size_t)(n0+row)*K + kt + kc*8;
                float4 u = *(const float4*)src, v = *(const float4*)(src+4);
                __align__(16) unsigned short tmp[8] =
                    {f2b(u.x),f2b(u.y),f2b(u.z),f2b(u.w),f2b(v.x),f2b(v.y),f2b(v.z),f2b(v.w)};
                *(bf16x8*)&Bs[row*64 + kc*8] = *(const bf16x8*)tmp;
            }
        }
        __syncthreads();
#pragma unroll
        for (int kg = 0; kg < 2; kg++) {
            bf16x8 af[4], bfr[4];
#pragma unroll
            for (int mi = 0; mi < 4; mi++)
                af[mi] = *(const bf16x8*)&As[(wm*64+mi*16+(lane&15))*64 + kg*32 + (lane>>4)*8];
#pragma unroll
            for (int ni = 0; ni < 4; ni++)
                bfr[ni] = *(const bf16x8*)&Bs[(wn*64+ni*16+(lane&15))*64 + kg*32 + (lane>>4)*8];
#pragma unroll
            for (int mi = 0; mi < 4; mi++)
#pragma unroll
                for (int ni = 0; ni < 4; ni++)
                    acc[mi][ni] = __builtin_amdgcn_mfma_f32_16x16x32_bf16(
                        af[mi], bfr[ni], acc[mi][ni], 0, 0, 0);
        }
    }

    const int cl = lane & 15, rg = lane >> 4;
    const int bct = m0 >> 9;
#pragma unroll
    for (int mi = 0; mi < 4; mi++) {
        const int rowb = m0 + wm*64 + mi*16 + rg*4;
#pragma unroll
        for (int ni = 0; ni < 4; ni++) {
            const int col = n0 + wn*64 + ni*16 + cl;
            const float bv = bias[col];
            const float cv = (MODE==1) ? ctx[(size_t)bct*HID + col] : 0.0f;
#pragma unroll
            for (int r = 0; r < 4; r++) {
                float val = acc[mi][ni][r] + bv;
                if (MODE==1) val = tanhf(val + cv);
                const size_t off = (size_t)(rowb+r)*N + col;
                if (MODE==0) ((float*)Cv)[off] = val;
                else ((unsigned short*)Cv)[off] = f2b(val);
            }
        }
    }
}

// ---------------------------------------------------------------------------
__global__ __launch_bounds__(256) void gate_kernel(
    const float* __restrict__ ctx, const float* __restrict__ Wg,
    const float* __restrict__ bg, float* __restrict__ gate)
{
    const int j = blockIdx.x * 256 + threadIdx.x;
    const int b = blockIdx.y;
    const float4* cp = (const float4*)(ctx + (size_t)b * HID);
    const float4* wp = (const float4*)(Wg + (size_t)j * HID);
    float acc = 0.0f;
#pragma unroll 4
    for (int k = 0; k < HID / 4; k++) {
        float4 c = cp[k], w = wp[k];
        acc += c.x * w.x + c.y * w.y + c.z * w.z + c.w * w.w;
    }
    gate[(size_t)b * HID + j] = sigm(acc + bg[j]);
}

__device__ __forceinline__ void poll_ge(const unsigned int* p, unsigned int tgt)
{
    while (__hip_atomic_load(p, __ATOMIC_RELAXED, __HIP_MEMORY_SCOPE_AGENT) < tgt)
        __builtin_amdgcn_s_sleep(2);
}

// ---------------------------------------------------------------------------
// XCD-local 4-stage GRU pipe.
// Batches split 16/16 (M=16 = MFMA M). Stage-halves pinned to XCDs via
// runtime XCC_ID + atomic rank (LDS>80KB forces 1 block/CU -> exactly 32
// blocks/XCD):  xcd0/1=R0  xcd2/3=P1  xcd4/5=R1  xcd6/7=P0 (half = xcd&1).
// Recurrence self-loop (publish/flag/h-stage) is intra-XCD (L2).
// Cross-XCD links are producer->consumer with slack only.
// Block rb owns 32 cols; 6 waves = 3 gates x 2 K-halves; wreg 32 frags/lane.
// h_lds XOR-swizzled (stride 17*128B, byte ^= (row&7)<<4) via pre-swizzled
// global source (m173 pattern) -> conflict-free ds_read_b128.
// Flag sets indexed by xcd; counters after set area.
// ---------------------------------------------------------------------------
__global__ __launch_bounds__(384, 1) void gru_pipe(
    const float* __restrict__ Wih0, const float* __restrict__ Whh0,
    const float* __restrict__ bih0, const float* __restrict__ bhh0,
    const float* __restrict__ Wih1, const float* __restrict__ Whh1,
    const float* __restrict__ bih1, const float* __restrict__ bhh1,
    const unsigned short* __restrict__ mixed,
    unsigned short* __restrict__ h1,
    unsigned short* __restrict__ h2,
    unsigned short* __restrict__ xgs,           // 4 x [RING][16][3072]
    unsigned int* __restrict__ flags)           // 8 sets x 32 x FSTR + counters
{
    __shared__ __align__(16) unsigned short h_lds[40*HSTR];  // >80KB: 1 block/CU
    __shared__ float sc[192*17];
    __shared__ int s_xcd, s_rank;

    const int tid = threadIdx.x;
    const int lane = tid & 63;
    const int w = tid >> 6;
    const int cl = lane & 15, kq = lane >> 4;

    if (tid == 0) {
        unsigned x;
        asm volatile("s_getreg_b32 %0, hwreg(HW_REG_XCC_ID, 0, 32)" : "=s"(x));
        x &= 7u;
        s_xcd = (int)x;
        s_rank = (int)atomicAdd(&flags[8*32*FSTR + x*16], 1u);
    }
    __syncthreads();
    const int xcd = s_xcd;
    const int rb  = s_rank & 31;
    const int half = xcd & 1;
    const int kind = xcd >> 1;            // 0=R0 1=P1 2=R1 3=P0
    const int col0 = rb * 32;
    const int bb   = half * 16;

    unsigned int* fsetb = flags;          // set i at flags + i*32*FSTR

    // ---- weights -> registers: 2 N-blocks x 16 k-groups (K-half kh) -------
    const int g = w >> 1, kh = w & 1;
    const float* Wsrc = (kind==0) ? Whh0 : (kind==1) ? Wih1
                      : (kind==2) ? Whh1 : Wih0;
    bf16x8 wreg[32];
#pragma unroll
    for (int nb = 0; nb < 2; nb++) {
        const float* wr = Wsrc + (size_t)(g*1024 + col0 + nb*16 + cl)*1024 + kh*512 + kq*8;
#pragma unroll
        for (int kg = 0; kg < 16; kg++) {
            float4 u = *(const float4*)(wr + (size_t)kg*32);
            float4 v = *(const float4*)(wr + (size_t)kg*32 + 4);
            __align__(16) unsigned short tmp[8] =
                {f2b(u.x),f2b(u.y),f2b(u.z),f2b(u.w),f2b(v.x),f2b(v.y),f2b(v.z),f2b(v.w)};
            wreg[nb*16 + kg] = *(const bf16x8*)tmp;
        }
    }
#pragma unroll
    for (int i = 0; i < 32; i++) asm volatile("" : "+v"(wreg[i]));

    const int rot = (cl & 7) << 4;
    const char* hbytes = (const char*)h_lds;

    // ring for this block's layer-half
    unsigned short* ring = xgs + (size_t)((kind==0 || kind==3) ? half : 2+half) * RS;

    if (kind == 0 || kind == 2) {
        // ====================== R stage (recurrence) ======================
        unsigned short* hdst = (kind == 0) ? h1 : h2;
        const float* bih = (kind == 0) ? bih0 : bih1;
        const float* bhh = (kind == 0) ? bhh0 : bhh1;
        const unsigned int* peers = fsetb + xcd*32*FSTR;
        const unsigned int* prod  = fsetb + ((kind==0) ? (6+half) : (2+half))*32*FSTR;
        unsigned int* myflag = (unsigned int*)(peers + rb*FSTR);

        const int fb = tid >> 4;              // 0..15 (batch) for tid<256
        const int fj = (tid & 15) * 2;        // col pair 0..30
        float hp0 = 0.f, hp1 = 0.f;
        float br0=0,br1=0,bz0=0,bz1=0,bni0=0,bni1=0,bnh0=0,bnh1=0;
        if (tid < 256) {
            const int jc = col0 + fj;
            br0 = bih[jc]         + bhh[jc];
            br1 = bih[jc+1]       + bhh[jc+1];
            bz0 = bih[HID+jc]     + bhh[HID+jc];
            bz1 = bih[HID+jc+1]   + bhh[HID+jc+1];
            bni0 = bih[2*HID+jc];    bni1 = bih[2*HID+jc+1];
            bnh0 = bhh[2*HID+jc];    bnh1 = bhh[2*HID+jc+1];
        }

        for (int t = 0; t < SEQT; t++) {
            if (w == 0 && lane < 32 && t > 0)
                poll_ge(&peers[lane*FSTR], (unsigned)t);          // intra-XCD
            if (w == 2 && lane < 32 && (t & 7) == 0) {
                const unsigned tgt = (t + 8 <= SEQT) ? (unsigned)(t + 8) : (unsigned)SEQT;
                poll_ge(&prod[lane*FSTR], tgt);                   // producer ahead
            }
            __syncthreads();

            // xg ring reads (agent atomics, stale-safe) — issue early
            uint32_t xr2=0, xz2=0, xn2=0;
            if (tid < 256) {
                const unsigned short* xp = ring + ((size_t)(t & (RING-1))*16 + fb)*3072;
                xr2 = __hip_atomic_load((const unsigned int*)(xp + col0 + fj),
                                        __ATOMIC_RELAXED, __HIP_MEMORY_SCOPE_AGENT);
                xz2 = __hip_atomic_load((const unsigned int*)(xp + 1024 + col0 + fj),
                                        __ATOMIC_RELAXED, __HIP_MEMORY_SCOPE_AGENT);
                xn2 = __hip_atomic_load((const unsigned int*)(xp + 2048 + col0 + fj),
                                        __ATOMIC_RELAXED, __HIP_MEMORY_SCOPE_AGENT);
            }
            if (t > 0) {
                for (int c = w; c < 32; c += 6) {                 // stage h[t-1]
                    const int r = c >> 1, hf = c & 1;
                    const char* src = (const char*)hdst
                        + (((size_t)(bb + r)*SEQT + (t-1))*HID)*2
                        + hf*1024 + ((lane*16) ^ ((r & 7) << 4));
                    __builtin_amdgcn_global_load_lds(
                        (const __attribute__((address_space(1))) void*)src,
                        (__attribute__((address_space(3))) void*)
                            ((char*)h_lds + r*2176 + hf*1024),
                        16, 0, 0);
                }
            }
            asm volatile("s_waitcnt vmcnt(0)" ::: "memory");
            __syncthreads();

            f32x4 A00={0.f,0.f,0.f,0.f}, A01=A00, A10=A00, A11=A00;
            if (t > 0) {
#pragma unroll
                for (int kg = 0; kg < 16; kg++) {
                    bf16x8 hv = *(const bf16x8*)(hbytes + cl*2176 +
                        ((kh*1024 + kg*64 + kq*16) ^ rot));
                    if (kg & 1) {
                        A01 = __builtin_amdgcn_mfma_f32_16x16x32_bf16(hv, wreg[kg],    A01, 0,0,0);
                        A11 = __builtin_amdgcn_mfma_f32_16x16x32_bf16(hv, wreg[16+kg], A11, 0,0,0);
                    } else {
                        A00 = __builtin_amdgcn_mfma_f32_16x16x32_bf16(hv, wreg[kg],    A00, 0,0,0);
                        A10 = __builtin_amdgcn_mfma_f32_16x16x32_bf16(hv, wreg[16+kg], A10, 0,0,0);
                    }
                }
            }
            f32x4 av0 = A00 + A01, av1 = A10 + A11;
#pragma unroll
            for (int r = 0; r < 4; r++) {
                sc[((g*4 + kh*2 + 0)*16 + kq*4 + r)*17 + cl] = av0[r];
                sc[((g*4 + kh*2 + 1)*16 + kq*4 + r)*17 + cl] = av1[r];
            }
            __syncthreads();

            if (tid < 256) {
                const int c0 = fj, nb = c0 >> 4, cc = c0 & 15;
                const float sr0 = sc[((0*4+nb)*16+fb)*17+cc]   + sc[((0*4+2+nb)*16+fb)*17+cc];
                const float sr1 = sc[((0*4+nb)*16+fb)*17+cc+1] + sc[((0*4+2+nb)*16+fb)*17+cc+1];
                const float sz0 = sc[((1*4+nb)*16+fb)*17+cc]   + sc[((1*4+2+nb)*16+fb)*17+cc];
                const float sz1 = sc[((1*4+nb)*16+fb)*17+cc+1] + sc[((1*4+2+nb)*16+fb)*17+cc+1];
                const float sn0 = sc[((2*4+nb)*16+fb)*17+cc]   + sc[((2*4+2+nb)*16+fb)*17+cc];
                const float sn1 = sc[((2*4+nb)*16+fb)*17+cc+1] + sc[((2*4+2+nb)*16+fb)*17+cc+1];
                const float r0 = sigm(b2f((unsigned short)(xr2 & 0xFFFF)) + sr0 + br0);
                const float r1 = sigm(b2f((unsigned short)(xr2 >> 16))    + sr1 + br1);
                const float z0 = sigm(b2f((unsigned short)(xz2 & 0xFFFF)) + sz0 + bz0);
                const float z1 = sigm(b2f((unsigned short)(xz2 >> 16))    + sz1 + bz1);
                const float n0 = tanhf(b2f((unsigned short)(xn2 & 0xFFFF)) + bni0 + r0*(sn0 + bnh0));
                const float n1 = tanhf(b2f((unsigned short)(xn2 >> 16))    + bni1 + r1*(sn1 + bnh1));
                const float h0 = (1.0f - z0)*n0 + z0*hp0;
                const float h1v = (1.0f - z1)*n1 + z1*hp1;
                hp0 = h0; hp1 = h1v;
                const uint32_t hv = (uint32_t)f2b(h0) | ((uint32_t)f2b(h1v) << 16);
                uint32_t* dst = (uint32_t*)(hdst + ((size_t)(bb+fb)*SEQT + t)*HID + col0 + fj);
                __hip_atomic_store(dst, hv, __ATOMIC_RELAXED, __HIP_MEMORY_SCOPE_AGENT);
            }
            asm volatile("s_waitcnt vmcnt(0)" ::: "memory");
            __syncthreads();
            if (tid == 0)
                __hip_atomic_store(myflag, (unsigned)(t+1),
                                   __ATOMIC_RELAXED, __HIP_MEMORY_SCOPE_AGENT);
        }
    } else {
        // ====================== P stage (feed-forward) ====================
        const unsigned short* src_base = (kind == 3) ? mixed : h1;
        const unsigned int* waitin = (kind == 1) ? (fsetb + (0+half)*32*FSTR) : nullptr;
        const unsigned int* bp = fsetb + ((kind==3) ? (0+half) : (4+half))*32*FSTR;
        unsigned int* myflag = fsetb + xcd*32*FSTR + rb*FSTR;

        for (int t = 0; t < SEQT; t++) {
            if (w == 0 && lane < 32 && waitin)
                poll_ge(&waitin[lane*FSTR], (unsigned)(t+1));     // h1[t] ready
            if (w == 1 && lane < 32 && t >= RING && (t & 7) == 0)
                poll_ge(&bp[lane*FSTR], (unsigned)(t - 24));      // ring slack
            __syncthreads();

            for (int c = w; c < 32; c += 6) {                     // stage src[t]
                const int r = c >> 1, hf = c & 1;
                const char* src = (const char*)src_base
                    + (((size_t)(bb + r)*SEQT + t)*HID)*2
                    + hf*1024 + ((lane*16) ^ ((r & 7) << 4));
                __builtin_amdgcn_global_load_lds(
                    (const __attribute__((address_space(1))) void*)src,
                    (__attribute__((address_space(3))) void*)
                        ((char*)h_lds + r*2176 + hf*1024),
                    16, 0, 0);
            }
            asm volatile("s_waitcnt vmcnt(0)" ::: "memory");
            __syncthreads();

            f32x4 A00={0.f,0.f,0.f,0.f}, A01=A00, A10=A00, A11=A00;
#pragma unroll
            for (int kg = 0; kg < 16; kg++) {
                bf16x8 hv = *(const bf16x8*)(hbytes + cl*2176 +
                    ((kh*1024 + kg*64 + kq*16) ^ rot));
                if (kg & 1) {
                    A01 = __builtin_amdgcn_mfma_f32_16x16x32_bf16(hv, wreg[kg],    A01, 0,0,0);
                    A11 = __builtin_amdgcn_mfma_f32_16x16x32_bf16(hv, wreg[16+kg], A11, 0,0,0);
                } else {
                    A00 = __builtin_amdgcn_mfma_f32_16x16x32_bf16(hv, wreg[kg],    A00, 0,0,0);
                    A10 = __builtin_amdgcn_mfma_f32_16x16x32_bf16(hv, wreg[16+kg], A10, 0,0,0);
                }
            }
            f32x4 av0 = A00 + A01, av1 = A10 + A11;
#pragma unroll
            for (int r = 0; r < 4; r++) {
                sc[((g*4 + kh*2 + 0)*16 + kq*4 + r)*17 + cl] = av0[r];
                sc[((g*4 + kh*2 + 1)*16 + kq*4 + r)*17 + cl] = av1[r];
            }
            __syncthreads();

            if (tid < 192) {
                const int fb = tid / 12, gi = tid % 12;
                const int gg = gi >> 2, c8 = (gi & 3) * 8;
                unsigned short v[8];
#pragma unroll
                for (int k = 0; k < 8; k++) {
                    const int c = c8 + k, nb = c >> 4, cc = c & 15;
                    v[k] = f2b(sc[((gg*4+nb)*16+fb)*17+cc] + sc[((gg*4+2+nb)*16+fb)*17+cc]);
                }
                const uint64_t lo = (uint64_t)v[0] | ((uint64_t)v[1]<<16)
                                  | ((uint64_t)v[2]<<32) | ((uint64_t)v[3]<<48);
                const uint64_t hi = (uint64_t)v[4] | ((uint64_t)v[5]<<16)
                                  | ((uint64_t)v[6]<<32) | ((uint64_t)v[7]<<48);
                uint64_t* dst = (uint64_t*)(ring + ((size_t)(t & (RING-1))*16 + fb)*3072
                                            + gg*1024 + col0 + c8);
                __hip_atomic_store(dst,   lo, __ATOMIC_RELAXED, __HIP_MEMORY_SCOPE_AGENT);
                __hip_atomic_store(dst+1, hi, __ATOMIC_RELAXED, __HIP_MEMORY_SCOPE_AGENT);
            }
            asm volatile("s_waitcnt vmcnt(0)" ::: "memory");
            __syncthreads();
            if (tid == 0)
                __hip_atomic_store(myflag, (unsigned)(t+1),
                                   __ATOMIC_RELAXED, __HIP_MEMORY_SCOPE_AGENT);
        }
    }
}

// ---------------------------------------------------------------------------
__global__ __launch_bounds__(256) void diag_kernel(float* __restrict__ out,
                                                   int n, float code)
{
    for (int i = blockIdx.x * 256 + threadIdx.x; i < n; i += gridDim.x * 256)
        out[i] = (i == 0) ? code : 0.0f;
}

// ---------------------------------------------------------------------------
extern "C" void kernel_launch(void* const* d_in, const int* in_sizes, int n_in,
                              void* d_out, int out_size, void* d_ws, size_t ws_size,
                              hipStream_t stream)
{
    const float* x      = (const float*)d_in[0];
    const float* ctx    = (const float*)d_in[1];
    const float* W_in   = (const float*)d_in[2];
    const float* b_in   = (const float*)d_in[3];
    const float* Wih0   = (const float*)d_in[4];
    const float* Whh0   = (const float*)d_in[5];
    const float* bih0   = (const float*)d_in[6];
    const float* bhh0   = (const float*)d_in[7];
    const float* Wih1   = (const float*)d_in[8];
    const float* Whh1   = (const float*)d_in[9];
    const float* bih1   = (const float*)d_in[10];
    const float* bhh1   = (const float*)d_in[11];
    const float* W_out  = (const float*)d_in[12];
    const float* b_out  = (const float*)d_in[13];
    const float* W_gate = (const float*)d_in[14];
    const float* b_gate = (const float*)d_in[15];
    float* out = (float*)d_out;

    const size_t MX  = (size_t)16384 * 1024 * 2;        // 32 MiB each
    const size_t XGS = (size_t)4 * RS * 2;              // 12 MiB
    const size_t GT  = (size_t)32 * 1024 * 4;
    const size_t FL  = (size_t)(8*32*FSTR + 256) * 4;   // sets + counters
    const size_t need = 3*MX + XGS + GT + FL;

    if (ws_size < need) {
        diag_kernel<<<2048, 256, 0, stream>>>(out, out_size, (float)(ws_size >> 20));
        return;
    }

    char* ws = (char*)d_ws;
    unsigned short* mixed = (unsigned short*)ws;
    unsigned short* h1    = (unsigned short*)(ws + MX);
    unsigned short* h2    = (unsigned short*)(ws + 2*MX);
    unsigned short* xgs   = (unsigned short*)(ws + 3*MX);
    float*          gate  = (float*)(ws + 3*MX + XGS);
    unsigned int*   flags = (unsigned int*)(ws + 3*MX + XGS + GT);

    hipMemsetAsync(flags, 0, FL, stream);
    gate_kernel<<<dim3(4, 32), 256, 0, stream>>>(ctx, W_gate, b_gate, gate);

    // mixed = tanh(x @ W_in^T + b_in + ctx[b]) -> bf16
    mfma_gemm<1, 1, 1><<<dim3(8, 128), 256, 0, stream>>>(
        x, W_in, b_in, ctx, nullptr, mixed, 1024, 1024);

    // XCD-local 4-stage pipelined GRU section
    gru_pipe<<<256, 384, 0, stream>>>(
        Wih0, Whh0, bih0, bhh0, Wih1, Whh1, bih1, bhh1,
        mixed, h1, h2, xgs, flags);

    // out = (h2 * (1+gate)) @ W_out^T + b_out -> f32
    mfma_gemm<2, 1, 0><<<dim3(8, 128), 256, 0, stream>>>(
        h2, W_out, b_out, nullptr, gate, out, 1024, 1024);
}